// Round 1
// baseline (933.476 us; speedup 1.0000x reference)
//
#include <hip/hip_runtime.h>
#include <hip/hip_bf16.h>

// Problem constants (shapes fixed by the reference)
#define SRCL 512
#define BSZ  16
#define SNTL 512
#define CDIM 512          // C == E == 512
#define KDIM 512
#define VOC  12000
#define EXTN 500
#define MROWS (SRCL*BSZ)  // 8192
#define TOTV (VOC+EXTN)   // 12500
#define NPAD 12032        // Wgen rows padded to 94*128 so GEMM2 has no bounds checks
#define LL_SIZE ((size_t)MROWS * TOTV)   // 102,400,000

typedef __attribute__((ext_vector_type(8))) short bf16x8;   // 8 bf16 (4 VGPRs)
typedef __attribute__((ext_vector_type(4))) float f32x4;

__device__ __forceinline__ void gload16(const void* g, void* l) {
  // async global->LDS, 16B per lane; LDS dest is wave-uniform base + lane*16
  __builtin_amdgcn_global_load_lds(
      (const __attribute__((address_space(1))) unsigned int*)g,
      (__attribute__((address_space(3))) unsigned int*)l, 16, 0, 0);
}

// ---------------------------------------------------------------------------
// fp32 -> bf16 conversion of concept_outs, W_transfer, W_gen (zero-padded rows)
// ---------------------------------------------------------------------------
__global__ void cvt_kernel(const float* __restrict__ co, const float* __restrict__ wt,
                           const float* __restrict__ wg,
                           __hip_bfloat16* __restrict__ cob,
                           __hip_bfloat16* __restrict__ wtb,
                           __hip_bfloat16* __restrict__ wgb) {
  const int stride = gridDim.x * blockDim.x;
  const int t0 = blockIdx.x * blockDim.x + threadIdx.x;
  for (int i = t0; i < MROWS*KDIM; i += stride) cob[i] = __float2bfloat16(co[i]);
  for (int i = t0; i < CDIM*KDIM;  i += stride) wtb[i] = __float2bfloat16(wt[i]);
  for (int i = t0; i < NPAD*KDIM;  i += stride)
    wgb[i] = __float2bfloat16(i < VOC*KDIM ? wg[i] : 0.f);
}

// ---------------------------------------------------------------------------
// bf16 MFMA GEMM, C = A(MxK) * B(NxK)^T  (both K-contiguous), m97 structure:
// 128x128 tile, BK=32, global_load_lds w=16, 4 waves x (4x4) 16x16x32 MFMAs.
// EPI=0: h = tanh(acc + bias[col]) -> bf16, ld=512
// EPI=1: logits = acc + bias[col<VOC] -> fp32 at row*12500+col (into d_out)
// ---------------------------------------------------------------------------
template<int EPI>
__launch_bounds__(256)
__global__ void gemm_bt(const short* __restrict__ A, const short* __restrict__ Bm,
                        const float* __restrict__ bias, void* __restrict__ outp) {
  __shared__ short As[128*32];
  __shared__ short Bs[128*32];
  const int tid  = threadIdx.x;
  const int wave = tid >> 6;
  const int lane = tid & 63;
  const int m0 = blockIdx.y * 128;
  const int n0 = blockIdx.x * 128;

  // staging: wave w stages rows [32w, 32w+32) of both tiles; lane -> (row, k8)
  const int lrow = lane >> 2;          // 0..15
  const int lkof = (lane & 3) * 8;     // k element offset
  const size_t aG0 = (size_t)(m0 + wave*32 + lrow) * KDIM + lkof;
  const size_t aG1 = aG0 + (size_t)16 * KDIM;
  const size_t bG0 = (size_t)(n0 + wave*32 + lrow) * KDIM + lkof;
  const size_t bG1 = bG0 + (size_t)16 * KDIM;
  short* lA0 = As + wave*1024;  short* lA1 = lA0 + 512;
  short* lB0 = Bs + wave*1024;  short* lB1 = lB0 + 512;

  // compute: wave (wm,wn) owns a 64x64 quadrant = 4x4 subtiles of 16x16
  const int wm = wave & 1, wn = wave >> 1;
  const int quad = lane >> 4, r16 = lane & 15;
  const int aoff = (wm*64 + r16)*32 + quad*8;
  const int boff = (wn*64 + r16)*32 + quad*8;

  f32x4 acc[4][4];
#pragma unroll
  for (int i = 0; i < 4; ++i)
#pragma unroll
    for (int j = 0; j < 4; ++j) acc[i][j] = (f32x4){0.f,0.f,0.f,0.f};

  for (int kt = 0; kt < KDIM/32; ++kt) {
    const int kof = kt * 32;
    __syncthreads();                       // prev iter's LDS reads done
    gload16(A  + aG0 + kof, lA0);
    gload16(A  + aG1 + kof, lA1);
    gload16(Bm + bG0 + kof, lB0);
    gload16(Bm + bG1 + kof, lB1);
    __syncthreads();                       // staging visible
    bf16x8 af[4], bf[4];
#pragma unroll
    for (int i = 0; i < 4; ++i) {
      af[i] = *(const bf16x8*)(As + aoff + i*512);   // ds_read_b128
      bf[i] = *(const bf16x8*)(Bs + boff + i*512);
    }
#pragma unroll
    for (int mi = 0; mi < 4; ++mi)
#pragma unroll
      for (int ni = 0; ni < 4; ++ni)
        acc[mi][ni] = __builtin_amdgcn_mfma_f32_16x16x32_bf16(af[mi], bf[ni], acc[mi][ni], 0, 0, 0);
  }

  // epilogue; C/D layout: col = lane&15, row = quad*4 + reg  (m89-verified)
#pragma unroll
  for (int mi = 0; mi < 4; ++mi) {
#pragma unroll
    for (int ni = 0; ni < 4; ++ni) {
#pragma unroll
      for (int r = 0; r < 4; ++r) {
        const int row = m0 + wm*64 + mi*16 + quad*4 + r;
        const int col = n0 + wn*64 + ni*16 + r16;
        float v = acc[mi][ni][r];
        if constexpr (EPI == 0) {
          v = tanhf(v + bias[col]);
          ((__hip_bfloat16*)outp)[(size_t)row * CDIM + col] = __float2bfloat16(v);
        } else {
          v += (col < VOC) ? bias[col] : 0.f;
          ((float*)outp)[(size_t)row * TOTV + col] = v;   // cols 12000..12031 are scratch, overwritten later
        }
      }
    }
  }
}

// ---------------------------------------------------------------------------
// gates = softmax(h @ W_div^T + b_div) per row; h read as bf16
// ---------------------------------------------------------------------------
__launch_bounds__(256)
__global__ void gates_kernel(const __hip_bfloat16* __restrict__ h,
                             const float* __restrict__ Wd, const float* __restrict__ bd,
                             float* __restrict__ gates) {
  __shared__ float scr[12];
  const int m = blockIdx.x;
  float d0 = 0.f, d1 = 0.f, d2 = 0.f;
  for (int c = threadIdx.x; c < CDIM; c += 256) {
    const float hv = __bfloat162float(h[(size_t)m*CDIM + c]);
    d0 += hv * Wd[c];
    d1 += hv * Wd[CDIM + c];
    d2 += hv * Wd[2*CDIM + c];
  }
  for (int o = 32; o; o >>= 1) {
    d0 += __shfl_down(d0, o, 64);
    d1 += __shfl_down(d1, o, 64);
    d2 += __shfl_down(d2, o, 64);
  }
  const int w = threadIdx.x >> 6;
  if ((threadIdx.x & 63) == 0) { scr[w*3] = d0; scr[w*3+1] = d1; scr[w*3+2] = d2; }
  __syncthreads();
  if (threadIdx.x == 0) {
    float g0 = bd[0], g1 = bd[1], g2 = bd[2];
    for (int i = 0; i < 4; ++i) { g0 += scr[i*3]; g1 += scr[i*3+1]; g2 += scr[i*3+2]; }
    const float mx = fmaxf(g0, fmaxf(g1, g2));
    const float e0 = __expf(g0-mx), e1 = __expf(g1-mx), e2 = __expf(g2-mx);
    const float inv = 1.f / (e0 + e1 + e2);
    gates[m*3+0] = e0*inv; gates[m*3+1] = e1*inv; gates[m*3+2] = e2*inv;
  }
}

// ---------------------------------------------------------------------------
// per-row: softmax(logits)*gen_gate, scatter-add copy probs, log -> ll
// one block per row m; full 12500-wide row lives in LDS (50 KB)
// ---------------------------------------------------------------------------
__launch_bounds__(256)
__global__ void finalize_kernel(float* __restrict__ out, const float* __restrict__ gates,
                                const int* __restrict__ copy_seq,
                                const float* __restrict__ align) {
  __shared__ float p[TOTV];
  __shared__ float scr[4];
  const int m = blockIdx.x;      // = s*16 + b
  const int b = m & 15;
  float* row = out + (size_t)m * TOTV;

  for (int i = threadIdx.x; i < VOC; i += 256) p[i] = row[i];
  for (int i = VOC + threadIdx.x; i < TOTV; i += 256) p[i] = 0.f;
  __syncthreads();

  float mx = -1e30f;
  for (int i = threadIdx.x; i < VOC; i += 256) mx = fmaxf(mx, p[i]);
  for (int o = 32; o; o >>= 1) mx = fmaxf(mx, __shfl_down(mx, o, 64));
  if ((threadIdx.x & 63) == 0) scr[threadIdx.x >> 6] = mx;
  __syncthreads();
  mx = fmaxf(fmaxf(scr[0], scr[1]), fmaxf(scr[2], scr[3]));
  __syncthreads();

  float sm = 0.f;
  for (int i = threadIdx.x; i < VOC; i += 256) {
    const float e = __expf(p[i] - mx);
    p[i] = e;
    sm += e;
  }
  for (int o = 32; o; o >>= 1) sm += __shfl_down(sm, o, 64);
  if ((threadIdx.x & 63) == 0) scr[threadIdx.x >> 6] = sm;
  __syncthreads();
  sm = scr[0] + scr[1] + scr[2] + scr[3];

  const float gen  = gates[m*3 + 0];
  const float mapg = gates[m*3 + 1];
  const float cpg  = gates[m*3 + 2];
  const float scale = gen / sm;
  for (int i = threadIdx.x; i < VOC; i += 256) p[i] *= scale;
  __syncthreads();

  // scatter-add: idx = copy_seq[t,b,j]; val = (j? map : copy)_gate * align[m,t]
  for (int t = threadIdx.x; t < SNTL; t += 256) {
    const float aw = align[(size_t)m * SNTL + t];
    const int2 cs = *(const int2*)&copy_seq[(t*BSZ + b)*2];
    atomicAdd(&p[cs.x], cpg  * aw);
    atomicAdd(&p[cs.y], mapg * aw);
  }
  __syncthreads();

  for (int i = threadIdx.x; i < TOTV; i += 256) row[i] = __logf(p[i] + 1e-12f);
}

// ---------------------------------------------------------------------------
// arc_ll = log(arc_weight + 1e-12)
// ---------------------------------------------------------------------------
__global__ void arc_kernel(const float* __restrict__ arc, float* __restrict__ out) {
  const int stride = gridDim.x * blockDim.x;
  for (int i = blockIdx.x * blockDim.x + threadIdx.x; i < SRCL*BSZ*SRCL; i += stride)
    out[i] = __logf(arc[i] + 1e-12f);
}

extern "C" void kernel_launch(void* const* d_in, const int* in_sizes, int n_in,
                              void* d_out, int out_size, void* d_ws, size_t ws_size,
                              hipStream_t stream) {
  (void)in_sizes; (void)n_in; (void)out_size; (void)ws_size;
  const float* align   = (const float*)d_in[0];
  const float* arc     = (const float*)d_in[1];
  const float* concept = (const float*)d_in[3];
  const int*   cseq    = (const int*)d_in[4];
  const float* Wt = (const float*)d_in[9];
  const float* bt = (const float*)d_in[10];
  const float* Wg = (const float*)d_in[11];
  const float* bg = (const float*)d_in[12];
  const float* Wd = (const float*)d_in[13];
  const float* bd = (const float*)d_in[14];
  float* out = (float*)d_out;

  // workspace layout (~28.4 MB total)
  __hip_bfloat16* cob = (__hip_bfloat16*)d_ws;           // 8192x512
  __hip_bfloat16* wtb = cob + (size_t)MROWS*KDIM;        // 512x512
  __hip_bfloat16* wgb = wtb + (size_t)CDIM*KDIM;         // 12032x512 (padded)
  __hip_bfloat16* hb  = wgb + (size_t)NPAD*KDIM;         // 8192x512
  float* gates = (float*)(hb + (size_t)MROWS*KDIM);      // 8192x3

  cvt_kernel<<<2048, 256, 0, stream>>>(concept, Wt, Wg, cob, wtb, wgb);
  gemm_bt<0><<<dim3(CDIM/128, MROWS/128), 256, 0, stream>>>(
      (const short*)cob, (const short*)wtb, bt, (void*)hb);
  gates_kernel<<<MROWS, 256, 0, stream>>>(hb, Wd, bd, gates);
  gemm_bt<1><<<dim3(NPAD/128, MROWS/128), 256, 0, stream>>>(
      (const short*)hb, (const short*)wgb, bg, (void*)out);
  finalize_kernel<<<MROWS, 256, 0, stream>>>(out, gates, cseq, align);
  arc_kernel<<<4096, 256, 0, stream>>>(arc, out + LL_SIZE);
}

// Round 2
// 800.769 us; speedup vs baseline: 1.1657x; 1.1657x over previous
//
#include <hip/hip_runtime.h>
#include <hip/hip_bf16.h>

// Problem constants (shapes fixed by the reference)
#define SRCL 512
#define BSZ  16
#define SNTL 512
#define CDIM 512          // C == E == 512
#define KDIM 512
#define VOC  12000
#define EXTN 500
#define MROWS (SRCL*BSZ)  // 8192
#define TOTV (VOC+EXTN)   // 12500
#define NPAD 12032        // Wgen rows padded to 94*128 so GEMM2 has no bounds checks
#define LL_SIZE ((size_t)MROWS * TOTV)   // 102,400,000

typedef __attribute__((ext_vector_type(8))) short bf16x8;   // 8 bf16 (4 VGPRs)
typedef __attribute__((ext_vector_type(4))) float f32x4;

__device__ __forceinline__ unsigned short f2bf(float x) {
  union { __hip_bfloat16 b; unsigned short u; } c;
  c.b = __float2bfloat16(x);
  return c.u;
}
__device__ __forceinline__ float bflo(unsigned int u) { return __uint_as_float(u << 16); }
__device__ __forceinline__ float bfhi(unsigned int u) { return __uint_as_float(u & 0xffff0000u); }

__device__ __forceinline__ void gload16(const void* g, void* l) {
  // async global->LDS, 16B per lane; LDS dest is wave-uniform base + lane*16
  __builtin_amdgcn_global_load_lds(
      (const __attribute__((address_space(1))) unsigned int*)g,
      (__attribute__((address_space(3))) unsigned int*)l, 16, 0, 0);
}

__device__ __forceinline__ float wred_max(float v) {
  for (int o = 32; o; o >>= 1) v = fmaxf(v, __shfl_down(v, o, 64));
  return v;
}
__device__ __forceinline__ float wred_sum(float v) {
  for (int o = 32; o; o >>= 1) v += __shfl_down(v, o, 64);
  return v;
}

// ---------------------------------------------------------------------------
// fp32 -> bf16 conversion (vectorized float4 -> ushort4)
// ---------------------------------------------------------------------------
__global__ void cvt_kernel(const float* __restrict__ co, const float* __restrict__ wt,
                           const float* __restrict__ wg,
                           unsigned short* __restrict__ cob,
                           unsigned short* __restrict__ wtb,
                           unsigned short* __restrict__ wgb) {
  const int stride = gridDim.x * blockDim.x;
  const int t0 = blockIdx.x * blockDim.x + threadIdx.x;
  for (int i = t0; i < MROWS*KDIM/4; i += stride) {
    const float4 v = ((const float4*)co)[i];
    ushort4 o; o.x = f2bf(v.x); o.y = f2bf(v.y); o.z = f2bf(v.z); o.w = f2bf(v.w);
    ((ushort4*)cob)[i] = o;
  }
  for (int i = t0; i < CDIM*KDIM/4; i += stride) {
    const float4 v = ((const float4*)wt)[i];
    ushort4 o; o.x = f2bf(v.x); o.y = f2bf(v.y); o.z = f2bf(v.z); o.w = f2bf(v.w);
    ((ushort4*)wtb)[i] = o;
  }
  for (int i = t0; i < NPAD*KDIM/4; i += stride) {
    float4 v = make_float4(0.f, 0.f, 0.f, 0.f);
    if (i < VOC*KDIM/4) v = ((const float4*)wg)[i];
    ushort4 o; o.x = f2bf(v.x); o.y = f2bf(v.y); o.z = f2bf(v.z); o.w = f2bf(v.w);
    ((ushort4*)wgb)[i] = o;
  }
}

// ---------------------------------------------------------------------------
// bf16 MFMA GEMM, C = A(MxK) * B(NxK)^T, m97 structure:
// 128x128 tile, BK=32, global_load_lds w=16, 4 waves x (4x4) 16x16x32 MFMAs.
// EPI=0: h = tanh(acc + bias[col]) -> bf16, ld=CDIM
// EPI=1: logits = acc + bias[col<VOC] -> fp32 at row*TOTV+col (into d_out)
// EPI=2: logits = acc + bias[col<VOC] -> bf16 at row*NPAD+col (into ws)
// ---------------------------------------------------------------------------
template<int EPI>
__launch_bounds__(256)
__global__ void gemm_bt(const short* __restrict__ A, const short* __restrict__ Bm,
                        const float* __restrict__ bias, void* __restrict__ outp) {
  __shared__ short As[128*32];
  __shared__ short Bs[128*32];
  const int tid  = threadIdx.x;
  const int wave = tid >> 6;
  const int lane = tid & 63;
  const int m0 = blockIdx.y * 128;
  const int n0 = blockIdx.x * 128;

  // staging: wave w stages rows [32w, 32w+32) of both tiles; lane -> (row, k8)
  const int lrow = lane >> 2;          // 0..15
  const int lkof = (lane & 3) * 8;     // k element offset
  const size_t aG0 = (size_t)(m0 + wave*32 + lrow) * KDIM + lkof;
  const size_t aG1 = aG0 + (size_t)16 * KDIM;
  const size_t bG0 = (size_t)(n0 + wave*32 + lrow) * KDIM + lkof;
  const size_t bG1 = bG0 + (size_t)16 * KDIM;
  short* lA0 = As + wave*1024;  short* lA1 = lA0 + 512;
  short* lB0 = Bs + wave*1024;  short* lB1 = lB0 + 512;

  // compute: wave (wm,wn) owns a 64x64 quadrant = 4x4 subtiles of 16x16
  const int wm = wave & 1, wn = wave >> 1;
  const int quad = lane >> 4, r16 = lane & 15;
  const int aoff = (wm*64 + r16)*32 + quad*8;
  const int boff = (wn*64 + r16)*32 + quad*8;

  f32x4 acc[4][4];
#pragma unroll
  for (int i = 0; i < 4; ++i)
#pragma unroll
    for (int j = 0; j < 4; ++j) acc[i][j] = (f32x4){0.f,0.f,0.f,0.f};

  for (int kt = 0; kt < KDIM/32; ++kt) {
    const int kof = kt * 32;
    __syncthreads();                       // prev iter's LDS reads done
    gload16(A  + aG0 + kof, lA0);
    gload16(A  + aG1 + kof, lA1);
    gload16(Bm + bG0 + kof, lB0);
    gload16(Bm + bG1 + kof, lB1);
    __syncthreads();                       // staging visible
    bf16x8 af[4], bf[4];
#pragma unroll
    for (int i = 0; i < 4; ++i) {
      af[i] = *(const bf16x8*)(As + aoff + i*512);   // ds_read_b128
      bf[i] = *(const bf16x8*)(Bs + boff + i*512);
    }
#pragma unroll
    for (int mi = 0; mi < 4; ++mi)
#pragma unroll
      for (int ni = 0; ni < 4; ++ni)
        acc[mi][ni] = __builtin_amdgcn_mfma_f32_16x16x32_bf16(af[mi], bf[ni], acc[mi][ni], 0, 0, 0);
  }

  // epilogue; C/D layout: col = lane&15, row = quad*4 + reg  (m89-verified)
#pragma unroll
  for (int mi = 0; mi < 4; ++mi) {
#pragma unroll
    for (int ni = 0; ni < 4; ++ni) {
#pragma unroll
      for (int r = 0; r < 4; ++r) {
        const int row = m0 + wm*64 + mi*16 + quad*4 + r;
        const int col = n0 + wn*64 + ni*16 + r16;
        float v = acc[mi][ni][r];
        if constexpr (EPI == 0) {
          v = tanhf(v + bias[col]);
          ((unsigned short*)outp)[(size_t)row * CDIM + col] = f2bf(v);
        } else if constexpr (EPI == 1) {
          v += (col < VOC) ? bias[col] : 0.f;
          ((float*)outp)[(size_t)row * TOTV + col] = v;   // pad cols overwritten later
        } else {
          v += (col < VOC) ? bias[col] : 0.f;
          ((unsigned short*)outp)[(size_t)row * NPAD + col] = f2bf(v);  // pad cols never read
        }
      }
    }
  }
}

// ---------------------------------------------------------------------------
// gates = softmax(h @ W_div^T + b_div) per row; h read as bf16
// ---------------------------------------------------------------------------
__launch_bounds__(256)
__global__ void gates_kernel(const __hip_bfloat16* __restrict__ h,
                             const float* __restrict__ Wd, const float* __restrict__ bd,
                             float* __restrict__ gates) {
  __shared__ float scr[12];
  const int m = blockIdx.x;
  float d0 = 0.f, d1 = 0.f, d2 = 0.f;
  for (int c = threadIdx.x; c < CDIM; c += 256) {
    const float hv = __bfloat162float(h[(size_t)m*CDIM + c]);
    d0 += hv * Wd[c];
    d1 += hv * Wd[CDIM + c];
    d2 += hv * Wd[2*CDIM + c];
  }
  d0 = wred_sum(d0); d1 = wred_sum(d1); d2 = wred_sum(d2);
  const int w = threadIdx.x >> 6;
  if ((threadIdx.x & 63) == 0) { scr[w*3] = d0; scr[w*3+1] = d1; scr[w*3+2] = d2; }
  __syncthreads();
  if (threadIdx.x == 0) {
    float g0 = bd[0], g1 = bd[1], g2 = bd[2];
    for (int i = 0; i < 4; ++i) { g0 += scr[i*3]; g1 += scr[i*3+1]; g2 += scr[i*3+2]; }
    const float mx = fmaxf(g0, fmaxf(g1, g2));
    const float e0 = __expf(g0-mx), e1 = __expf(g1-mx), e2 = __expf(g2-mx);
    const float inv = 1.f / (e0 + e1 + e2);
    gates[m*3+0] = e0*inv; gates[m*3+1] = e1*inv; gates[m*3+2] = e2*inv;
  }
}

// ---------------------------------------------------------------------------
// per-row: softmax(logits)*gen_gate, scatter-add copy probs, log -> ll
// one block (1024 thr = 16 waves) per row; 50 KB LDS -> 2 blocks/CU = 32 w/CU
// BF16L=1: logits are bf16 ld=NPAD (in ws); BF16L=0: fp32 ld=TOTV (in d_out)
// ---------------------------------------------------------------------------
template<int BF16L>
__launch_bounds__(1024)
__global__ void finalize_kernel(const void* __restrict__ lg, float* __restrict__ out,
                                const float* __restrict__ gates,
                                const int* __restrict__ copy_seq,
                                const float* __restrict__ align) {
  __shared__ __align__(16) float p[TOTV];
  __shared__ float scr[16];
  const int m = blockIdx.x;      // = s*16 + b
  const int b = m & 15;
  const int tid = threadIdx.x;
  float* row = out + (size_t)m * TOTV;

  // load logits into LDS, tracking max
  float mx = -1e30f;
  if constexpr (BF16L) {
    const uint4* rowv = (const uint4*)((const unsigned short*)lg + (size_t)m * NPAD);
    for (int i = tid; i < VOC/8; i += 1024) {
      const uint4 q = rowv[i];
      const float v0 = bflo(q.x), v1 = bfhi(q.x), v2 = bflo(q.y), v3 = bfhi(q.y);
      const float v4 = bflo(q.z), v5 = bfhi(q.z), v6 = bflo(q.w), v7 = bfhi(q.w);
      const int base = i*8;
      p[base+0]=v0; p[base+1]=v1; p[base+2]=v2; p[base+3]=v3;
      p[base+4]=v4; p[base+5]=v5; p[base+6]=v6; p[base+7]=v7;
      mx = fmaxf(mx, fmaxf(fmaxf(fmaxf(v0,v1),fmaxf(v2,v3)), fmaxf(fmaxf(v4,v5),fmaxf(v6,v7))));
    }
  } else {
    const float4* rowv = (const float4*)row;
    for (int i = tid; i < VOC/4; i += 1024) {
      const float4 v = rowv[i];
      ((float4*)p)[i] = v;
      mx = fmaxf(mx, fmaxf(fmaxf(v.x, v.y), fmaxf(v.z, v.w)));
    }
  }
  for (int i = VOC + tid; i < TOTV; i += 1024) p[i] = 0.f;

  mx = wred_max(mx);
  if ((tid & 63) == 0) scr[tid >> 6] = mx;
  __syncthreads();
  mx = scr[0];
#pragma unroll
  for (int i = 1; i < 16; ++i) mx = fmaxf(mx, scr[i]);
  __syncthreads();   // scr reuse

  float sm = 0.f;
  for (int i = tid; i < VOC; i += 1024) {
    const float e = __expf(p[i] - mx);
    p[i] = e;
    sm += e;
  }
  sm = wred_sum(sm);
  if ((tid & 63) == 0) scr[tid >> 6] = sm;
  __syncthreads();
  sm = scr[0];
#pragma unroll
  for (int i = 1; i < 16; ++i) sm += scr[i];

  const float gen  = gates[m*3 + 0];
  const float mapg = gates[m*3 + 1];
  const float cpg  = gates[m*3 + 2];
  const float scale = gen / sm;      // out_i = log(scale*(e_i + s_i/scale) + eps), exact algebra
  const float inv   = sm / gen;
  const float cw = cpg * inv, mw = mapg * inv;

  // scatter-add (1024 threads cover SNT=512 in one shot)
  if (tid < SNTL) {
    const float aw = align[(size_t)m * SNTL + tid];
    const int2 cs = *(const int2*)&copy_seq[(tid*BSZ + b)*2];
    atomicAdd(&p[cs.x], cw * aw);
    atomicAdd(&p[cs.y], mw * aw);
  }
  __syncthreads();

  for (int i = tid; i < TOTV/4; i += 1024) {
    const float4 v = ((const float4*)p)[i];
    float4 r;
    r.x = __logf(fmaf(v.x, scale, 1e-12f));
    r.y = __logf(fmaf(v.y, scale, 1e-12f));
    r.z = __logf(fmaf(v.z, scale, 1e-12f));
    r.w = __logf(fmaf(v.w, scale, 1e-12f));
    ((float4*)row)[i] = r;
  }
}

// ---------------------------------------------------------------------------
// arc_ll = log(arc_weight + 1e-12), float4-vectorized
// ---------------------------------------------------------------------------
__global__ void arc_kernel(const float4* __restrict__ arc, float4* __restrict__ out) {
  const int i = blockIdx.x * blockDim.x + threadIdx.x;
  if (i < (SRCL*BSZ*SRCL)/4) {
    const float4 v = arc[i];
    float4 r;
    r.x = __logf(v.x + 1e-12f);
    r.y = __logf(v.y + 1e-12f);
    r.z = __logf(v.z + 1e-12f);
    r.w = __logf(v.w + 1e-12f);
    out[i] = r;
  }
}

extern "C" void kernel_launch(void* const* d_in, const int* in_sizes, int n_in,
                              void* d_out, int out_size, void* d_ws, size_t ws_size,
                              hipStream_t stream) {
  (void)in_sizes; (void)n_in; (void)out_size;
  const float* align   = (const float*)d_in[0];
  const float* arc     = (const float*)d_in[1];
  const float* concept = (const float*)d_in[3];
  const int*   cseq    = (const int*)d_in[4];
  const float* Wt = (const float*)d_in[9];
  const float* bt = (const float*)d_in[10];
  const float* Wg = (const float*)d_in[11];
  const float* bg = (const float*)d_in[12];
  const float* Wd = (const float*)d_in[13];
  const float* bd = (const float*)d_in[14];
  float* out = (float*)d_out;

  // workspace layout
  unsigned short* cob = (unsigned short*)d_ws;          // 8192x512 bf16
  unsigned short* wtb = cob + (size_t)MROWS*KDIM;       // 512x512
  unsigned short* wgb = wtb + (size_t)CDIM*KDIM;        // 12032x512 (padded)
  unsigned short* hb  = wgb + (size_t)NPAD*KDIM;        // 8192x512
  float* gates = (float*)(hb + (size_t)MROWS*KDIM);     // 8192x3
  unsigned short* logitsb = (unsigned short*)(gates + (size_t)MROWS*3);  // 8192x12032 bf16
  const size_t need = (size_t)((char*)(logitsb + (size_t)MROWS*NPAD) - (char*)d_ws);
  const bool use_bf16_logits = (ws_size >= need);   // ws_size constant per session

  cvt_kernel<<<2048, 256, 0, stream>>>(concept, Wt, Wg, cob, wtb, wgb);
  gemm_bt<0><<<dim3(CDIM/128, MROWS/128), 256, 0, stream>>>(
      (const short*)cob, (const short*)wtb, bt, (void*)hb);
  gates_kernel<<<MROWS, 256, 0, stream>>>((const __hip_bfloat16*)hb, Wd, bd, gates);
  if (use_bf16_logits) {
    gemm_bt<2><<<dim3(NPAD/128, MROWS/128), 256, 0, stream>>>(
        (const short*)hb, (const short*)wgb, bg, (void*)logitsb);
    finalize_kernel<1><<<MROWS, 1024, 0, stream>>>(logitsb, out, gates, cseq, align);
  } else {
    gemm_bt<1><<<dim3(NPAD/128, MROWS/128), 256, 0, stream>>>(
        (const short*)hb, (const short*)wgb, bg, (void*)out);
    finalize_kernel<0><<<MROWS, 1024, 0, stream>>>(out, out, gates, cseq, align);
  }
  arc_kernel<<<4096, 256, 0, stream>>>((const float4*)arc, (float4*)(out + LL_SIZE));
}